// Round 6
// baseline (23.501 us; speedup 1.0000x reference)
//
#include <hip/hip_runtime.h>
#include <cmath>

// RoiPoolingConv: per-ROI crop + legacy-TF bilinear resize.
// img [1,H,W,C] f32, rois [1,R,4] i32 (x,y,w,h), out [1,R,P,P,C] f32.
//
// R3: skip exactly-zero-weight gathers (wx==0 / wy==0 are bit-exact
// passthroughs), reuse registers for clamped-duplicate coords.
// R5 (=R4 fixed): nontemporal output stores via clang ext_vector float4
// (HIP_vector_type struct is rejected by the builtin). Write stream is
// never re-read; keep it out of L2 so gather lines survive.
// One wave per output pixel, 4 waves / 256-thread block, single kernel.

typedef float nvf4 __attribute__((ext_vector_type(4)));

__global__ __launch_bounds__(256) void roi_pool_kernel(
    const float* __restrict__ img, const int* __restrict__ rois,
    float* __restrict__ out, int P, int H, int W, int C, int npix) {
  const int g = blockIdx.x * 4 + (threadIdx.x >> 6);  // global output pixel
  if (g >= npix) return;
  const int lane = threadIdx.x & 63;
  const int pp = P * P;
  const int r = g / pp;
  const int ij = g - r * pp;
  const int i = ij / P;
  const int j = ij - i * P;

  const int4 roi = *reinterpret_cast<const int4*>(rois + r * 4);
  const int x = roi.x, y = roi.y, wd = roi.z, ht = roi.w;

  const float Pf = (float)P;
  // Match reference fp32 semantics exactly:
  const float sy = (float)y + (float)i * ((float)ht / Pf);
  const float sx = (float)x + (float)j * ((float)wd / Pf);
  const float fy = floorf(sy);
  const float fx = floorf(sx);
  int y0 = (int)fy;
  int x0 = (int)fx;
  int y1 = min(y0 + 1, y + ht - 1);   // from UNclipped y0
  int x1 = min(x0 + 1, x + wd - 1);
  y0 = min(max(y0, 0), H - 1);
  y1 = min(max(y1, 0), H - 1);
  x0 = min(max(x0, 0), W - 1);
  x1 = min(max(x1, 0), W - 1);
  const float wy = sy - fy;           // from UNclipped floor
  const float wx = sx - fx;
  const float omwx = 1.0f - wx;
  const float omwy = 1.0f - wy;
  const bool xnz = (wx != 0.0f);      // wave-uniform
  const bool ynz = (wy != 0.0f);

  const float* __restrict__ p00 = img + ((size_t)y0 * W + x0) * C;
  const float* __restrict__ p01 = img + ((size_t)y0 * W + x1) * C;
  const float* __restrict__ p10 = img + ((size_t)y1 * W + x0) * C;
  const float* __restrict__ p11 = img + ((size_t)y1 * W + x1) * C;
  float* __restrict__ po = out + (size_t)g * C;

#define LERP4(dst, lo, hi, wlo, whi)          \
  dst.x = lo.x * wlo + hi.x * whi;            \
  dst.y = lo.y * wlo + hi.y * whi;            \
  dst.z = lo.z * wlo + hi.z * whi;            \
  dst.w = lo.w * wlo + hi.w * whi;

  // lane covers channels [lane*8, lane*8+8): two float4 per source pixel.
  for (int c = lane * 8; c < C; c += 64 * 8) {
    const float4 a00 = *reinterpret_cast<const float4*>(p00 + c);
    const float4 b00 = *reinterpret_cast<const float4*>(p00 + c + 4);

    float4 a01, b01;                  // only meaningful when xnz
    float4 ta, tb;                    // top-row lerp
    if (xnz) {
      if (x1 != x0) {
        a01 = *reinterpret_cast<const float4*>(p01 + c);
        b01 = *reinterpret_cast<const float4*>(p01 + c + 4);
      } else {
        a01 = a00; b01 = b00;
      }
      LERP4(ta, a00, a01, omwx, wx)
      LERP4(tb, b00, b01, omwx, wx)
    } else {
      ta = a00; tb = b00;             // v00*1 + v01*0 == v00 exactly
    }

    float4 oa, ob;
    if (ynz) {
      float4 a10, b10;
      if (y1 != y0) {
        a10 = *reinterpret_cast<const float4*>(p10 + c);
        b10 = *reinterpret_cast<const float4*>(p10 + c + 4);
      } else {
        a10 = a00; b10 = b00;
      }
      float4 ba, bb;                  // bottom-row lerp
      if (xnz) {
        float4 a11, b11;
        if (x1 != x0) {
          if (y1 != y0) {
            a11 = *reinterpret_cast<const float4*>(p11 + c);
            b11 = *reinterpret_cast<const float4*>(p11 + c + 4);
          } else {
            a11 = a01; b11 = b01;
          }
        } else {
          a11 = a10; b11 = b10;
        }
        LERP4(ba, a10, a11, omwx, wx)
        LERP4(bb, b10, b11, omwx, wx)
      } else {
        ba = a10; bb = b10;
      }
      LERP4(oa, ta, ba, omwy, wy)
      LERP4(ob, tb, bb, omwy, wy)
    } else {
      oa = ta; ob = tb;               // top*1 + bot*0 == top exactly
    }

    // Output is write-once, never re-read: bypass L2 (nt flag) so the
    // streaming store doesn't evict gather lines.
    nvf4 va = {oa.x, oa.y, oa.z, oa.w};
    nvf4 vb = {ob.x, ob.y, ob.z, ob.w};
    __builtin_nontemporal_store(va, reinterpret_cast<nvf4*>(po + c));
    __builtin_nontemporal_store(vb, reinterpret_cast<nvf4*>(po + c + 4));
  }
#undef LERP4
}

extern "C" void kernel_launch(void* const* d_in, const int* in_sizes, int n_in,
                              void* d_out, int out_size, void* d_ws, size_t ws_size,
                              hipStream_t stream) {
  const float* img = (const float*)d_in[0];
  const int* rois = (const int*)d_in[1];
  float* out = (float*)d_out;

  const int H = 200, W = 200, C = 512;
  const int R = in_sizes[1] / 4;                    // 300
  const int pp = out_size / (R * C);                // P*P = 49
  int P = 1;
  while ((P + 1) * (P + 1) <= pp) ++P;              // isqrt -> 7

  const int npix = R * pp;                          // 14,700 output pixels
  const int blocks = (npix + 3) / 4;                // 4 waves (pixels) / block
  roi_pool_kernel<<<blocks, 256, 0, stream>>>(img, rois, out, P, H, W, C, npix);
}

// Round 7
// 22.028 us; speedup vs baseline: 1.0669x; 1.0669x over previous
//
#include <hip/hip_runtime.h>
#include <cmath>

// RoiPoolingConv: per-ROI crop + legacy-TF bilinear resize.
// img [1,H,W,C] f32, rois [1,R,4] i32 (x,y,w,h), out [1,R,P,P,C] f32.
//
// Final structure (R3, re-confirmed R6 after nt-store revert):
//  - one wave per output pixel, 4 waves / 256-thread block, single kernel
//  - skip exactly-zero-weight gathers: wx==0 (j==0 or P|w) makes the x1
//    column's contribution bit-exactly zero -> don't load it; same for
//    wy==0 / bottom row. Clamped-duplicate coords reuse registers.
//  - plain float4 stores (nt stores regressed: R5, 22.2 -> 23.5 us).
// Traffic-bound: ~121 MB logical @ ~5.45 TB/s (87% of achieved-copy BW).

__global__ __launch_bounds__(256) void roi_pool_kernel(
    const float* __restrict__ img, const int* __restrict__ rois,
    float* __restrict__ out, int P, int H, int W, int C, int npix) {
  const int g = blockIdx.x * 4 + (threadIdx.x >> 6);  // global output pixel
  if (g >= npix) return;
  const int lane = threadIdx.x & 63;
  const int pp = P * P;
  const int r = g / pp;
  const int ij = g - r * pp;
  const int i = ij / P;
  const int j = ij - i * P;

  const int4 roi = *reinterpret_cast<const int4*>(rois + r * 4);
  const int x = roi.x, y = roi.y, wd = roi.z, ht = roi.w;

  const float Pf = (float)P;
  // Match reference fp32 semantics exactly:
  const float sy = (float)y + (float)i * ((float)ht / Pf);
  const float sx = (float)x + (float)j * ((float)wd / Pf);
  const float fy = floorf(sy);
  const float fx = floorf(sx);
  int y0 = (int)fy;
  int x0 = (int)fx;
  int y1 = min(y0 + 1, y + ht - 1);   // from UNclipped y0
  int x1 = min(x0 + 1, x + wd - 1);
  y0 = min(max(y0, 0), H - 1);
  y1 = min(max(y1, 0), H - 1);
  x0 = min(max(x0, 0), W - 1);
  x1 = min(max(x1, 0), W - 1);
  const float wy = sy - fy;           // from UNclipped floor
  const float wx = sx - fx;
  const float omwx = 1.0f - wx;
  const float omwy = 1.0f - wy;
  const bool xnz = (wx != 0.0f);      // wave-uniform
  const bool ynz = (wy != 0.0f);

  const float* __restrict__ p00 = img + ((size_t)y0 * W + x0) * C;
  const float* __restrict__ p01 = img + ((size_t)y0 * W + x1) * C;
  const float* __restrict__ p10 = img + ((size_t)y1 * W + x0) * C;
  const float* __restrict__ p11 = img + ((size_t)y1 * W + x1) * C;
  float* __restrict__ po = out + (size_t)g * C;

#define LERP4(dst, lo, hi, wlo, whi)          \
  dst.x = lo.x * wlo + hi.x * whi;            \
  dst.y = lo.y * wlo + hi.y * whi;            \
  dst.z = lo.z * wlo + hi.z * whi;            \
  dst.w = lo.w * wlo + hi.w * whi;

  // lane covers channels [lane*8, lane*8+8): two float4 per source pixel.
  for (int c = lane * 8; c < C; c += 64 * 8) {
    const float4 a00 = *reinterpret_cast<const float4*>(p00 + c);
    const float4 b00 = *reinterpret_cast<const float4*>(p00 + c + 4);

    float4 a01, b01;                  // only meaningful when xnz
    float4 ta, tb;                    // top-row lerp
    if (xnz) {
      if (x1 != x0) {
        a01 = *reinterpret_cast<const float4*>(p01 + c);
        b01 = *reinterpret_cast<const float4*>(p01 + c + 4);
      } else {
        a01 = a00; b01 = b00;
      }
      LERP4(ta, a00, a01, omwx, wx)
      LERP4(tb, b00, b01, omwx, wx)
    } else {
      ta = a00; tb = b00;             // v00*1 + v01*0 == v00 exactly
    }

    float4 oa, ob;
    if (ynz) {
      float4 a10, b10;
      if (y1 != y0) {
        a10 = *reinterpret_cast<const float4*>(p10 + c);
        b10 = *reinterpret_cast<const float4*>(p10 + c + 4);
      } else {
        a10 = a00; b10 = b00;
      }
      float4 ba, bb;                  // bottom-row lerp
      if (xnz) {
        float4 a11, b11;
        if (x1 != x0) {
          if (y1 != y0) {
            a11 = *reinterpret_cast<const float4*>(p11 + c);
            b11 = *reinterpret_cast<const float4*>(p11 + c + 4);
          } else {
            a11 = a01; b11 = b01;
          }
        } else {
          a11 = a10; b11 = b10;
        }
        LERP4(ba, a10, a11, omwx, wx)
        LERP4(bb, b10, b11, omwx, wx)
      } else {
        ba = a10; bb = b10;
      }
      LERP4(oa, ta, ba, omwy, wy)
      LERP4(ob, tb, bb, omwy, wy)
    } else {
      oa = ta; ob = tb;               // top*1 + bot*0 == top exactly
    }

    *reinterpret_cast<float4*>(po + c) = oa;
    *reinterpret_cast<float4*>(po + c + 4) = ob;
  }
#undef LERP4
}

extern "C" void kernel_launch(void* const* d_in, const int* in_sizes, int n_in,
                              void* d_out, int out_size, void* d_ws, size_t ws_size,
                              hipStream_t stream) {
  const float* img = (const float*)d_in[0];
  const int* rois = (const int*)d_in[1];
  float* out = (float*)d_out;

  const int H = 200, W = 200, C = 512;
  const int R = in_sizes[1] / 4;                    // 300
  const int pp = out_size / (R * C);                // P*P = 49
  int P = 1;
  while ((P + 1) * (P + 1) <= pp) ++P;              // isqrt -> 7

  const int npix = R * pp;                          // 14,700 output pixels
  const int blocks = (npix + 3) / 4;                // 4 waves (pixels) / block
  roi_pool_kernel<<<blocks, 256, 0, stream>>>(img, rois, out, P, H, W, C, npix);
}